// Round 20
// baseline (340.095 us; speedup 1.0000x reference)
//
#include <hip/hip_runtime.h>
#include <hip/hip_bf16.h>
#include <cstdint>

#define DEV static __device__ __forceinline__

typedef __attribute__((ext_vector_type(8))) short short8;
typedef __attribute__((ext_vector_type(4))) float f32x4;
typedef __attribute__((ext_vector_type(2))) float f32x2;

DEV uint32_t bf16rne(float f) {
    uint32_t u = __float_as_uint(f);
    uint32_t r = u + 0x7FFFu + ((u >> 16) & 1u);
    return r >> 16;
}
DEV float bf16tof(uint32_t h) { return __uint_as_float((h & 0xFFFFu) << 16); }
DEV float hsig(float z) { return fminf(fmaxf(0.2f * z + 0.5f, 0.f), 1.f); }
DEV float lrelu(float x) { return x >= 0.f ? x : 0.3f * x; }
DEV float ftanh(float x) {
    float e = __expf(2.0f * x);
    return 1.0f - 2.0f * __builtin_amdgcn_rcpf(e + 1.0f);
}

DEV void gload16(const void* g, void* l) {
    __builtin_amdgcn_global_load_lds(
        reinterpret_cast<const __attribute__((address_space(1))) uint32_t*>(
            reinterpret_cast<uintptr_t>(g)),
        reinterpret_cast<__attribute__((address_space(3))) uint32_t*>(
            reinterpret_cast<uintptr_t>(l)),
        16, 0, 0);
}

#define HH 82
#define WW 67
#define PIX (HH * WW)   // 5494
#define BB 64
#define TT 24

#define NXZ 8442        // xz blocks: ceil(64*24*21*67 / 256)
#define NPREP 512       // prep blocks appended to the k_xz launch

// ---------------- fat kernel 1: xz (vertical-4 depth-1) + prep tail ----------------
__global__ __launch_bounds__(256) void k_xz(
    const float* __restrict__ inp, const float* __restrict__ wx,
    const float* __restrict__ bl, uint2* __restrict__ xz,
    const float* __restrict__ w1, const float* __restrict__ w2,
    const float* __restrict__ w3,
    ushort* __restrict__ w1t, ushort* __restrict__ w2t, ushort* __restrict__ w3t,
    uint4* __restrict__ z1, uint4* __restrict__ z2, uint4* __restrict__ z3)
{
    if (blockIdx.x >= NXZ) {
        const int Z1 = 852480, Z2 = 447488;
        const int W2 = 204800, W3 = 1048576, W1 = 12288, Z3 = 64;
        const int total = Z1 + Z2 + W2 + W3 + W1 + Z3;
        for (int id = (blockIdx.x - NXZ) * 256 + threadIdx.x; id < total;
             id += NPREP * 256) {
            if (id < Z1) {
                z1[id] = make_uint4(0, 0, 0, 0);
            } else if (id < Z1 + Z2) {
                z2[id - Z1] = make_uint4(0, 0, 0, 0);
            } else if (id < Z1 + Z2 + W2) {
                int idx = id - (Z1 + Z2);
                int n = idx / 1600, k = idx - n * 1600;
                w2t[idx] = (ushort)bf16rne(w2[(size_t)k * 128 + n]);
            } else if (id < Z1 + Z2 + W2 + W3) {
                int idx = id - (Z1 + Z2 + W2);
                int n = idx >> 11, k = idx & 2047;
                w3t[idx] = (ushort)bf16rne(w3[(size_t)k * 512 + n]);
            } else if (id < Z1 + Z2 + W2 + W3 + W1) {
                int idx = id - (Z1 + Z2 + W2 + W3);
                int n = idx / 192, k = idx % 192;
                w1t[idx] = (k < 150) ? (ushort)bf16rne(w1[(size_t)k * 64 + n])
                                     : (ushort)0;
            } else {
                z3[id - (Z1 + Z2 + W2 + W3 + W1)] = make_uint4(0, 0, 0, 0);
            }
        }
        return;
    }

    const int id = blockIdx.x * 256 + threadIdx.x;
    const int x  = id % 67;
    const int g  = (id / 67) % 21;
    const int bt = id / (67 * 21);
    if (bt >= BB * TT) return;
    const int y0 = g * 4;
    const float* img = inp + (size_t)bt * (PIX * 6);

    f32x2 a01[4], a23[4];
    const f32x2 bias01 = {bl[0], bl[1]};
    const f32x2 bias23 = {bl[2], bl[3]};
    #pragma unroll
    for (int o = 0; o < 4; ++o) { a01[o] = bias01; a23[o] = bias23; }

    #pragma unroll
    for (int rr = 0; rr < 6; ++rr) {
        const int iy = y0 - 1 + rr;
        if (iy < 0 || iy >= HH) continue;

        f32x2 vf[9];
        #pragma unroll
        for (int q = 0; q < 9; ++q) vf[q] = (f32x2){0.f, 0.f};
        const float* rp = img + (size_t)iy * 402 + (x - 1) * 6;
        if (x > 0) {
            vf[0] = *(const f32x2*)(rp);
            vf[1] = *(const f32x2*)(rp + 2);
            vf[2] = *(const f32x2*)(rp + 4);
        }
        vf[3] = *(const f32x2*)(rp + 6);
        vf[4] = *(const f32x2*)(rp + 8);
        vf[5] = *(const f32x2*)(rp + 10);
        if (x < 66) {
            vf[6] = *(const f32x2*)(rp + 12);
            vf[7] = *(const f32x2*)(rp + 14);
            vf[8] = *(const f32x2*)(rp + 16);
        }

        #pragma unroll
        for (int o = 0; o < 4; ++o) {
            const int dy = rr - o;
            if (dy < 0 || dy > 2) continue;
            #pragma unroll
            for (int kx = 0; kx < 3; ++kx) {
                const float* w6 = wx + (dy * 3 + kx) * 24;
                #pragma unroll
                for (int ci = 0; ci < 6; ++ci) {
                    const f32x2 w01 = *(const f32x2*)(w6 + ci * 4);
                    const f32x2 w23 = *(const f32x2*)(w6 + ci * 4 + 2);
                    const int fi = kx * 6 + ci;
                    const float s = vf[fi >> 1][fi & 1];
                    a01[o] += s * w01;
                    a23[o] += s * w23;
                }
            }
        }
    }

    #pragma unroll
    for (int o = 0; o < 4; ++o) {
        const int y = y0 + o;
        if (y < HH) {
            uint32_t lo = bf16rne(a01[o][0]) | (bf16rne(a01[o][1]) << 16);
            uint32_t hi = bf16rne(a23[o][0]) | (bf16rne(a23[o][1]) << 16);
            xz[((size_t)bt * HH + y) * WW + x] = make_uint2(lo, hi);
        }
    }
}

// ---------------- Kernel 2: LSTM, 4 blocks per image (quarter split) ----------------
// Block qb of image b owns rows r0=qb*21 .. r0+nrows-1 (21,21,21,19).
// Boundary rows exchanged with up to 2 neighbors via parity-indexed gxi +
// per-block flag chain (round-10 protocol generalized).
__global__ __launch_bounds__(512) void k_lstm(
    const uint2* __restrict__ xz, const float* __restrict__ wh,
    float* __restrict__ hout, int* __restrict__ gxi, int* __restrict__ flags)
{
    __shared__ float hb[2][23 * WW];     // 12,328 B (nrows+2 halo rows)
    __shared__ uint2 xt[2][1408];        // 22,528 B
    const int bid = blockIdx.x;
    const int b = bid >> 2, qb = bid & 3;
    const int r0 = qb * 21;
    const int nrows = (qb == 3) ? 19 : 21;
    const int tid = threadIdx.x;

    float whr[9][4];
    #pragma unroll
    for (int k = 0; k < 9; ++k)
        #pragma unroll
        for (int g = 0; g < 4; ++g) whr[k][g] = wh[k * 4 + g];

    for (int i = tid; i < 23 * WW; i += 512) hb[0][i] = 0.f;

    const bool active = tid < nrows * 23;
    const int r  = active ? tid / 23 : 0;       // own row 0..nrows-1
    const int gr = r0 + r;                      // global image row
    const int lr = r + 1;                       // hb local row (halo at 0)
    const int x0 = (tid % 23) * 3;
    const int len = active ? ((x0 + 3 <= WW) ? 3 : (WW - x0)) : 0;
    const bool wr_top = active && (r == 0) && (qb > 0);
    const bool wr_bot = active && (r == nrows - 1) && (qb < 3);
    float c[3];
    #pragma unroll
    for (int j = 0; j < 3; ++j) c[j] = 0.f;

    const int base_px = (r0 * WW) & ~1;         // 16B-aligned staging base
    const int end_px = (r0 + nrows) * WW;
    const int nch = (end_px - base_px + 1) >> 1;
    const char* xzb = (const char*)xz + (((size_t)b * TT) * PIX + base_px) * 8;
    int* myflag = flags + bid;
    // gxi slot: ((bid*2 + par)*2 + side)*68 ; side 0 = my top row, 1 = my bottom row
    #define GX(bb, par, side) (((((bb) * 2) + (par)) * 2 + (side)) * 68)

    #pragma unroll
    for (int k = 0; k < 2; ++k) {
        int idx = tid + k * 512;
        if (idx < nch)
            gload16(xzb + (size_t)idx * 16, (char*)xt[0] + (size_t)idx * 16);
    }
    __syncthreads();

    int cur = 0;
    #pragma unroll 1
    for (int t = 0; t < TT; ++t) {
        const int nxt = cur ^ 1;
        const int par = (t + 1) & 1;
        if (t < TT - 1) {
            const char* srcn = xzb + (size_t)(t + 1) * (PIX * 8);
            #pragma unroll
            for (int k = 0; k < 2; ++k) {
                int idx = tid + k * 512;
                if (idx < nch)
                    gload16(srcn + (size_t)idx * 16,
                            (char*)xt[nxt] + (size_t)idx * 16);
            }
        }
        if (active) {
            float z[3][4];
            #pragma unroll
            for (int j = 0; j < 3; ++j) {
                int xi = x0 + j; if (xi > WW - 1) xi = WW - 1;
                uint2 zp = xt[cur][gr * WW + xi - base_px];
                z[j][0] = bf16tof(zp.x); z[j][1] = bf16tof(zp.x >> 16);
                z[j][2] = bf16tof(zp.y); z[j][3] = bf16tof(zp.y >> 16);
            }
            #pragma unroll
            for (int ky = 0; ky < 3; ++ky) {
                int giy = gr + ky - 1;
                if (giy < 0 || giy >= HH) continue;
                const float* hr = &hb[cur][(giy - r0 + 1) * WW];
                #pragma unroll
                for (int dx = -1; dx < 4; ++dx) {
                    int xi = x0 + dx;
                    if (xi < 0 || xi >= WW) continue;
                    float hv = hr[xi];
                    #pragma unroll
                    for (int kx = 0; kx < 3; ++kx) {
                        int xo = dx - kx + 1;
                        if (xo < 0 || xo > 2) continue;
                        #pragma unroll
                        for (int g = 0; g < 4; ++g)
                            z[xo][g] = fmaf(hv, whr[ky * 3 + kx][g], z[xo][g]);
                    }
                }
            }
            float* hw = &hb[nxt][lr * WW];
            #pragma unroll
            for (int j = 0; j < 3; ++j) {
                float fi = hsig(z[j][0]), ff = hsig(z[j][1]), fo = hsig(z[j][3]);
                float cn = ff * c[j] + fi * ftanh(z[j][2]);
                c[j] = cn;
                if (j < len) {
                    float hv = fo * ftanh(cn);
                    hw[x0 + j] = hv;
                    if (wr_top)
                        atomicExch(&gxi[GX(bid, par, 0) + x0 + j],
                                   __float_as_int(hv));
                    if (wr_bot)
                        atomicExch(&gxi[GX(bid, par, 1) + x0 + j],
                                   __float_as_int(hv));
                }
            }
        }
        __syncthreads();                 // LDS + atomics + staged slab drained
        if (tid == 0) {
            atomicExch(myflag, t + 1);
            if (qb > 0)
                while (atomicAdd(flags + bid - 1, 0) < t + 1) { __builtin_amdgcn_s_sleep(8); }
            if (qb < 3)
                while (atomicAdd(flags + bid + 1, 0) < t + 1) { __builtin_amdgcn_s_sleep(8); }
        }
        __syncthreads();
        if (tid < WW) {
            if (qb > 0) {                // halo above = neighbor's bottom row
                int v = atomicAdd(&gxi[GX(bid - 1, par, 1) + tid], 0);
                hb[nxt][tid] = __int_as_float(v);
            }
            if (qb < 3) {                // halo below = neighbor's top row
                int v = atomicAdd(&gxi[GX(bid + 1, par, 0) + tid], 0);
                hb[nxt][(nrows + 1) * WW + tid] = __int_as_float(v);
            }
        }
        __syncthreads();
        cur = nxt;
    }
    float* ho = hout + (size_t)b * PIX + (size_t)(r0 * WW);
    const float* src = hb[cur] + WW;     // skip top halo row
    for (int i = tid; i < nrows * WW; i += 512)
        ho[i] = src[i];
}

// ---------------- conv1 im2col: A1[m][192] bf16, m=(b,y,x) of [64][41][34] ----------------
__global__ __launch_bounds__(256) void k_im2col(
    const float* __restrict__ hin, const float* __restrict__ tar,
    uint* __restrict__ A1)
{
    const int id = blockIdx.x * 256 + threadIdx.x;
    const int p = id % 28;
    const int m = id / 28;
    if (m >= 89216) return;
    uint* dst = A1 + (size_t)m * 96;
    if (p >= 25) {
        uint* q = dst + 75 + (p - 25) * 7;
        #pragma unroll
        for (int i = 0; i < 7; ++i) q[i] = 0;
        return;
    }
    const int x = m % 34;
    const int y = (m / 34) % 41;
    const int b = m / 1394;
    const int ky = p / 5, kx = p % 5;
    const int iy = 2 * y + ky - 1;
    const int ix = 2 * x + kx - 2;
    float v[6] = {0.f, 0.f, 0.f, 0.f, 0.f, 0.f};
    if (iy >= 0 && iy < HH && ix >= 0 && ix < WW) {
        const int pi = b * PIX + iy * WW + ix;
        v[0] = hin[pi];
        const float* tp = tar + (size_t)pi * 5;
        #pragma unroll
        for (int c = 0; c < 5; ++c) v[c + 1] = tp[c];
    }
    uint* q = dst + p * 3;
    q[0] = bf16rne(v[0]) | (bf16rne(v[1]) << 16);
    q[1] = bf16rne(v[2]) | (bf16rne(v[3]) << 16);
    q[2] = bf16rne(v[4]) | (bf16rne(v[5]) << 16);
}

// ---------------- conv1 GEMM: 256M x 64N tile, K=192 (3 chunks), 4 waves on M ----------------
__global__ __launch_bounds__(256) void k_gemm1(
    const ushort* __restrict__ A1, const ushort* __restrict__ w1t,
    const float* __restrict__ b1, ushort* __restrict__ x1p)
{
    constexpr int M = 89216;
    __shared__ ushort At[256 * 64];
    __shared__ ushort Bl[64 * 64];

    const int tid = threadIdx.x;
    const int wid = tid >> 6, lane = tid & 63;
    const int m0 = blockIdx.x * 256;
    const int swz = (((lane & 7) ^ ((lane >> 3) & 7)) << 3);

    int arow[8], brow[2];
    #pragma unroll
    for (int i = 0; i < 8; ++i) {
        int row = wid * 64 + i * 8 + (lane >> 3);
        int m = m0 + row; if (m > M - 1) m = M - 1;
        arow[i] = m * 192;
    }
    #pragma unroll
    for (int i = 0; i < 2; ++i) {
        int row = wid * 16 + i * 8 + (lane >> 3);
        brow[i] = row * 192;
    }

    f32x4 acc[4][4];
    #pragma unroll
    for (int i = 0; i < 4; ++i)
        #pragma unroll
        for (int j = 0; j < 4; ++j) acc[i][j] = (f32x4){0.f, 0.f, 0.f, 0.f};

    #pragma unroll 1
    for (int kp = 0; kp < 3; ++kp) {
        const int koff = kp * 64;
        #pragma unroll
        for (int i = 0; i < 8; ++i)
            gload16(A1 + arow[i] + koff + swz,
                    (void*)(At + (wid * 64 + i * 8) * 64));
        #pragma unroll
        for (int i = 0; i < 2; ++i)
            gload16(w1t + brow[i] + koff + swz,
                    (void*)(Bl + (wid * 16 + i * 8) * 64));
        __syncthreads();
        #pragma unroll
        for (int ks = 0; ks < 2; ++ks) {
            short8 af[4], bf[4];
            const int lc = ks * 64 + ((lane >> 4) << 4);
            #pragma unroll
            for (int mf = 0; mf < 4; ++mf) {
                int row = wid * 64 + mf * 16 + (lane & 15);
                af[mf] = *(const short8*)((const char*)At + row * 128 + (lc ^ ((row & 7) << 4)));
            }
            #pragma unroll
            for (int nf = 0; nf < 4; ++nf) {
                int row = nf * 16 + (lane & 15);
                bf[nf] = *(const short8*)((const char*)Bl + row * 128 + (lc ^ ((row & 7) << 4)));
            }
            #pragma unroll
            for (int mf = 0; mf < 4; ++mf)
                #pragma unroll
                for (int nf = 0; nf < 4; ++nf)
                    acc[mf][nf] = __builtin_amdgcn_mfma_f32_16x16x32_bf16(
                        af[mf], bf[nf], acc[mf][nf], 0, 0, 0);
        }
        __syncthreads();
    }

    #pragma unroll
    for (int nf = 0; nf < 4; ++nf) {
        int n = nf * 16 + (lane & 15);
        float bias = b1[n];
        #pragma unroll
        for (int mf = 0; mf < 4; ++mf) {
            int mbase = m0 + wid * 64 + mf * 16 + ((lane >> 4) << 2);
            #pragma unroll
            for (int r = 0; r < 4; ++r) {
                int m = mbase + r;
                if (m < M) {
                    int x = m % 34, y = (m / 34) % 41, b = m / 1394;
                    float v = lrelu(acc[mf][nf][r] + bias);
                    x1p[((size_t)(b * 45 + y + 2) * 37 + (x + 1)) * 64 + n] =
                        (ushort)bf16rne(v);
                }
            }
        }
    }
}

// ---------------- MFMA implicit-GEMM conv (conv2 / conv3), 128M x 64N tile ----------------
template<bool IS3>
__global__ __launch_bounds__(256) void k_convm(
    const ushort* __restrict__ Ain, const ushort* __restrict__ Bt,
    const float* __restrict__ p0, const float* __restrict__ p1,
    const float* __restrict__ p2, const float* __restrict__ p3,
    ushort* __restrict__ outp)
{
    constexpr int OH = IS3 ? 20 : 21, OW = IS3 ? 16 : 17;
    constexpr int PH = IS3 ? 23 : 45, PW = IS3 ? 19 : 37;
    constexpr int CIN = IS3 ? 128 : 64;
    constexpr int KW_ = IS3 ? 4 : 5;
    constexpr int KK  = IS3 ? 16 : 25;
    constexpr int STR = IS3 ? 1 : 2;
    constexpr int HALVES = CIN / 64;
    constexpr int MPB = OH * OW;
    constexpr int M = 64 * MPB;
    constexpr int KTOT = KK * CIN;

    __shared__ ushort At[128 * 64];
    __shared__ ushort Bl[64 * 64];

    const int tid = threadIdx.x;
    const int wid = tid >> 6, lane = tid & 63;
    const int m0 = blockIdx.x * 128;
    const int n0 = blockIdx.y * 64;
    const int wr = wid >> 1, wc = wid & 1;

    const int swz = (((lane & 7) ^ ((lane >> 3) & 7)) << 3);

    int arow_base[4], brow_base[2];
    #pragma unroll
    for (int i = 0; i < 4; ++i) {
        int row = wid * 32 + i * 8 + (lane >> 3);
        int m = m0 + row; if (m > M - 1) m = M - 1;
        int b = m / MPB, r = m % MPB;
        int y = r / OW, x = r % OW;
        arow_base[i] = ((b * PH + y * STR) * PW + x * STR) * CIN;
    }
    #pragma unroll
    for (int i = 0; i < 2; ++i) {
        int row = wid * 16 + i * 8 + (lane >> 3);
        brow_base[i] = (n0 + row) * KTOT;
    }

    f32x4 acc[4][2];
    #pragma unroll
    for (int i = 0; i < 4; ++i)
        #pragma unroll
        for (int j = 0; j < 2; ++j) acc[i][j] = (f32x4){0.f, 0.f, 0.f, 0.f};

    #pragma unroll 1
    for (int kp = 0; kp < KK; ++kp) {
        const int ky = kp / KW_, kx = kp % KW_;
        const int aoff = (ky * PW + kx) * CIN;
        #pragma unroll
        for (int h = 0; h < HALVES; ++h) {
            const int koff = h * 64;
            #pragma unroll
            for (int i = 0; i < 4; ++i)
                gload16(Ain + arow_base[i] + aoff + koff + swz,
                        (void*)(At + (wid * 32 + i * 8) * 64));
            #pragma unroll
            for (int i = 0; i < 2; ++i)
                gload16(Bt + brow_base[i] + kp * CIN + koff + swz,
                        (void*)(Bl + (wid * 16 + i * 8) * 64));
            __syncthreads();
            #pragma unroll
            for (int ks = 0; ks < 2; ++ks) {
                short8 af[4], bf[2];
                const int lc = ks * 64 + ((lane >> 4) << 4);
                #pragma unroll
                for (int mf = 0; mf < 4; ++mf) {
                    int row = wr * 64 + mf * 16 + (lane & 15);
                    af[mf] = *(const short8*)((const char*)At + row * 128 + (lc ^ ((row & 7) << 4)));
                }
                #pragma unroll
                for (int nf = 0; nf < 2; ++nf) {
                    int row = wc * 32 + nf * 16 + (lane & 15);
                    bf[nf] = *(const short8*)((const char*)Bl + row * 128 + (lc ^ ((row & 7) << 4)));
                }
                #pragma unroll
                for (int mf = 0; mf < 4; ++mf)
                    #pragma unroll
                    for (int nf = 0; nf < 2; ++nf)
                        acc[mf][nf] = __builtin_amdgcn_mfma_f32_16x16x32_bf16(
                            af[mf], bf[nf], acc[mf][nf], 0, 0, 0);
            }
            __syncthreads();
        }
    }

    if (IS3) {
        #pragma unroll
        for (int nf = 0; nf < 2; ++nf) {
            int n = n0 + wc * 32 + nf * 16 + (lane & 15);
            float sc = p0[n] * rsqrtf(p3[n] + 1e-3f);
            float sh = p1[n] - p2[n] * sc;
            #pragma unroll
            for (int mf = 0; mf < 4; ++mf) {
                int mbase = m0 + wr * 64 + mf * 16 + ((lane >> 4) << 2);
                #pragma unroll
                for (int r = 0; r < 4; ++r) {
                    float v = lrelu(acc[mf][nf][r] * sc + sh);
                    outp[(size_t)(mbase + r) * 512 + n] = (ushort)bf16rne(v);
                }
            }
        }
    } else {
        #pragma unroll
        for (int nf = 0; nf < 2; ++nf) {
            int n = n0 + wc * 32 + nf * 16 + (lane & 15);
            float bias = p0[n];
            #pragma unroll
            for (int mf = 0; mf < 4; ++mf) {
                int mbase = m0 + wr * 64 + mf * 16 + ((lane >> 4) << 2);
                #pragma unroll
                for (int r = 0; r < 4; ++r) {
                    int m = mbase + r;
                    if (m < M) {
                        int b = m / MPB, rr = m % MPB;
                        int y = rr / OW, x = rr % OW;
                        float v = lrelu(acc[mf][nf][r] + bias);
                        outp[((size_t)((b * 23) + (y + 1)) * 19 + (x + 1)) * 128 + n] =
                            (ushort)bf16rne(v);
                    }
                }
            }
        }
    }
}

// ---------------- Kernel 6: conv4, 256-thread blocks, 4 waves split input-x ----------------
__global__ __launch_bounds__(256) void k_conv4(
    const ushort* __restrict__ x3, const float* __restrict__ w4,
    const float* __restrict__ b4, float* __restrict__ out)
{
    __shared__ float red[4][16];
    const int b = blockIdx.x / 19, y = blockIdx.x % 19;
    const int wid = threadIdx.x >> 6, lane = threadIdx.x & 63;
    const int c0 = lane * 8;
    float acc[15];
    #pragma unroll
    for (int x = 0; x < 15; ++x) acc[x] = 0.f;
    #pragma unroll 1
    for (int ky = 0; ky < 4; ++ky) {
        int iy = y + ky - 1;
        if (iy < 0 || iy >= 20) continue;
        float w[4][8];
        #pragma unroll
        for (int kx = 0; kx < 4; ++kx) {
            const float4 wa = *(const float4*)(w4 + (ky * 4 + kx) * 512 + c0);
            const float4 wb = *(const float4*)(w4 + (ky * 4 + kx) * 512 + c0 + 4);
            w[kx][0] = wa.x; w[kx][1] = wa.y; w[kx][2] = wa.z; w[kx][3] = wa.w;
            w[kx][4] = wb.x; w[kx][5] = wb.y; w[kx][6] = wb.z; w[kx][7] = wb.w;
        }
        #pragma unroll
        for (int ixl = 0; ixl < 4; ++ixl) {
            const int ix = wid * 4 + ixl;
            uint4 u = *(const uint4*)(x3 + ((size_t)(b * 20 + iy) * 16 + ix) * 512 + c0);
            float v[8];
            v[0] = bf16tof(u.x); v[1] = bf16tof(u.x >> 16);
            v[2] = bf16tof(u.y); v[3] = bf16tof(u.y >> 16);
            v[4] = bf16tof(u.z); v[5] = bf16tof(u.z >> 16);
            v[6] = bf16tof(u.w); v[7] = bf16tof(u.w >> 16);
            #pragma unroll
            for (int kx = 0; kx < 4; ++kx) {
                int x = ix - kx + 1;
                if (x < 0 || x > 14) continue;
                float s = 0.f;
                #pragma unroll
                for (int c = 0; c < 8; ++c) s = fmaf(v[c], w[kx][c], s);
                acc[x] += s;
            }
        }
    }
    #pragma unroll
    for (int x = 0; x < 15; ++x) {
        float s = acc[x];
        #pragma unroll
        for (int off = 32; off > 0; off >>= 1)
            s += __shfl_down(s, off);
        if (lane == 0) red[wid][x] = s;
    }
    __syncthreads();
    if (threadIdx.x < 15) {
        float s = red[0][threadIdx.x] + red[1][threadIdx.x] +
                  red[2][threadIdx.x] + red[3][threadIdx.x] + b4[0];
        out[(size_t)blockIdx.x * 15 + threadIdx.x] = s;
    }
}

extern "C" void kernel_launch(void* const* d_in, const int* in_sizes, int n_in,
                              void* d_out, int out_size, void* d_ws, size_t ws_size,
                              hipStream_t stream)
{
    const float* inp  = (const float*)d_in[0];
    const float* tar  = (const float*)d_in[1];
    const float* wx   = (const float*)d_in[2];
    const float* wh   = (const float*)d_in[3];
    const float* bl   = (const float*)d_in[4];
    const float* w1   = (const float*)d_in[5];
    const float* b1   = (const float*)d_in[6];
    const float* w2   = (const float*)d_in[7];
    const float* b2   = (const float*)d_in[8];
    const float* w3   = (const float*)d_in[9];
    const float* gam  = (const float*)d_in[10];
    const float* bet  = (const float*)d_in[11];
    const float* mean = (const float*)d_in[12];
    const float* var  = (const float*)d_in[13];
    const float* w4   = (const float*)d_in[14];
    const float* b4   = (const float*)d_in[15];
    float* out = (float*)d_out;

    char* ws = (char*)d_ws;
    uint2*  xz    = (uint2*)(ws);
    ushort* A1    = (ushort*)(ws);
    ushort* x3b   = (ushort*)(ws);
    float*  hfin  = (float*)(ws + 67510272);
    ushort* x1p   = (ushort*)(ws + 68916736);
    ushort* x2p   = (ushort*)(ws + 82556416);
    ushort* w2t   = (ushort*)(ws + 89716224);
    ushort* w3t   = (ushort*)(ws + 90125824);
    ushort* w1t   = (ushort*)(ws + 92222976);
    int*    gxi   = (int*)(ws + 92247552);     // 278,528 B (256 x 2 x 2 x 68)
    int*    flags = (int*)(ws + 92526080);     // 1,024 B

    k_xz<<<NXZ + NPREP, 256, 0, stream>>>(inp, wx, bl, xz,
                                          w1, w2, w3, w1t, w2t, w3t,
                                          (uint4*)x1p, (uint4*)x2p, (uint4*)flags);
    k_lstm<<<BB * 4, 512, 0, stream>>>(xz, wh, hfin, gxi, flags);

    k_im2col<<<(89216 * 28 + 255) / 256, 256, 0, stream>>>(hfin, tar, (uint*)A1);
    k_gemm1<<<349, 256, 0, stream>>>(A1, w1t, b1, x1p);

    dim3 g2(179, 2);
    k_convm<false><<<g2, 256, 0, stream>>>(x1p, w2t, b2, nullptr, nullptr, nullptr, x2p);
    dim3 g3(160, 8);
    k_convm<true><<<g3, 256, 0, stream>>>(x2p, w3t, gam, bet, mean, var, x3b);

    k_conv4<<<BB * 19, 256, 0, stream>>>(x3b, w4, b4, out);
}

// Round 21
// 325.683 us; speedup vs baseline: 1.0443x; 1.0443x over previous
//
#include <hip/hip_runtime.h>
#include <hip/hip_bf16.h>
#include <cstdint>

#define DEV static __device__ __forceinline__

typedef __attribute__((ext_vector_type(8))) short short8;
typedef __attribute__((ext_vector_type(4))) float f32x4;
typedef __attribute__((ext_vector_type(2))) float f32x2;

DEV uint32_t bf16rne(float f) {
    uint32_t u = __float_as_uint(f);
    uint32_t r = u + 0x7FFFu + ((u >> 16) & 1u);
    return r >> 16;
}
DEV float bf16tof(uint32_t h) { return __uint_as_float((h & 0xFFFFu) << 16); }
DEV float hsig(float z) { return fminf(fmaxf(0.2f * z + 0.5f, 0.f), 1.f); }
DEV float lrelu(float x) { return x >= 0.f ? x : 0.3f * x; }
DEV float ftanh(float x) {
    float e = __expf(2.0f * x);
    return 1.0f - 2.0f * __builtin_amdgcn_rcpf(e + 1.0f);
}

DEV void gload16(const void* g, void* l) {
    __builtin_amdgcn_global_load_lds(
        reinterpret_cast<const __attribute__((address_space(1))) uint32_t*>(
            reinterpret_cast<uintptr_t>(g)),
        reinterpret_cast<__attribute__((address_space(3))) uint32_t*>(
            reinterpret_cast<uintptr_t>(l)),
        16, 0, 0);
}

#define HH 82
#define WW 67
#define PIX (HH * WW)   // 5494
#define BB 64
#define TT 24

#define NXZ 8442        // xz blocks: ceil(64*24*21*67 / 256)
#define NPREP 512       // prep blocks appended to the k_xz launch

// ---------------- fat kernel 1: xz (vertical-4 depth-1) + prep tail ----------------
__global__ __launch_bounds__(256) void k_xz(
    const float* __restrict__ inp, const float* __restrict__ wx,
    const float* __restrict__ bl, uint2* __restrict__ xz,
    const float* __restrict__ w1, const float* __restrict__ w2,
    const float* __restrict__ w3,
    ushort* __restrict__ w1t, ushort* __restrict__ w2t, ushort* __restrict__ w3t,
    uint4* __restrict__ z1, uint4* __restrict__ z2, uint4* __restrict__ z3)
{
    if (blockIdx.x >= NXZ) {
        const int Z1 = 852480, Z2 = 447488;
        const int W2 = 204800, W3 = 1048576, W1 = 12288, Z3 = 32;
        const int total = Z1 + Z2 + W2 + W3 + W1 + Z3;
        for (int id = (blockIdx.x - NXZ) * 256 + threadIdx.x; id < total;
             id += NPREP * 256) {
            if (id < Z1) {
                z1[id] = make_uint4(0, 0, 0, 0);
            } else if (id < Z1 + Z2) {
                z2[id - Z1] = make_uint4(0, 0, 0, 0);
            } else if (id < Z1 + Z2 + W2) {
                int idx = id - (Z1 + Z2);
                int n = idx / 1600, k = idx - n * 1600;
                w2t[idx] = (ushort)bf16rne(w2[(size_t)k * 128 + n]);
            } else if (id < Z1 + Z2 + W2 + W3) {
                int idx = id - (Z1 + Z2 + W2);
                int n = idx >> 11, k = idx & 2047;
                w3t[idx] = (ushort)bf16rne(w3[(size_t)k * 512 + n]);
            } else if (id < Z1 + Z2 + W2 + W3 + W1) {
                int idx = id - (Z1 + Z2 + W2 + W3);
                int n = idx / 192, k = idx % 192;
                w1t[idx] = (k < 150) ? (ushort)bf16rne(w1[(size_t)k * 64 + n])
                                     : (ushort)0;
            } else {
                z3[id - (Z1 + Z2 + W2 + W3 + W1)] = make_uint4(0, 0, 0, 0);
            }
        }
        return;
    }

    const int id = blockIdx.x * 256 + threadIdx.x;
    const int x  = id % 67;
    const int g  = (id / 67) % 21;
    const int bt = id / (67 * 21);
    if (bt >= BB * TT) return;
    const int y0 = g * 4;
    const float* img = inp + (size_t)bt * (PIX * 6);

    f32x2 a01[4], a23[4];
    const f32x2 bias01 = {bl[0], bl[1]};
    const f32x2 bias23 = {bl[2], bl[3]};
    #pragma unroll
    for (int o = 0; o < 4; ++o) { a01[o] = bias01; a23[o] = bias23; }

    #pragma unroll
    for (int rr = 0; rr < 6; ++rr) {
        const int iy = y0 - 1 + rr;
        if (iy < 0 || iy >= HH) continue;

        f32x2 vf[9];
        #pragma unroll
        for (int q = 0; q < 9; ++q) vf[q] = (f32x2){0.f, 0.f};
        const float* rp = img + (size_t)iy * 402 + (x - 1) * 6;
        if (x > 0) {
            vf[0] = *(const f32x2*)(rp);
            vf[1] = *(const f32x2*)(rp + 2);
            vf[2] = *(const f32x2*)(rp + 4);
        }
        vf[3] = *(const f32x2*)(rp + 6);
        vf[4] = *(const f32x2*)(rp + 8);
        vf[5] = *(const f32x2*)(rp + 10);
        if (x < 66) {
            vf[6] = *(const f32x2*)(rp + 12);
            vf[7] = *(const f32x2*)(rp + 14);
            vf[8] = *(const f32x2*)(rp + 16);
        }

        #pragma unroll
        for (int o = 0; o < 4; ++o) {
            const int dy = rr - o;
            if (dy < 0 || dy > 2) continue;
            #pragma unroll
            for (int kx = 0; kx < 3; ++kx) {
                const float* w6 = wx + (dy * 3 + kx) * 24;
                #pragma unroll
                for (int ci = 0; ci < 6; ++ci) {
                    const f32x2 w01 = *(const f32x2*)(w6 + ci * 4);
                    const f32x2 w23 = *(const f32x2*)(w6 + ci * 4 + 2);
                    const int fi = kx * 6 + ci;
                    const float s = vf[fi >> 1][fi & 1];
                    a01[o] += s * w01;
                    a23[o] += s * w23;
                }
            }
        }
    }

    #pragma unroll
    for (int o = 0; o < 4; ++o) {
        const int y = y0 + o;
        if (y < HH) {
            uint32_t lo = bf16rne(a01[o][0]) | (bf16rne(a01[o][1]) << 16);
            uint32_t hi = bf16rne(a23[o][0]) | (bf16rne(a23[o][1]) << 16);
            xz[((size_t)bt * HH + y) * WW + x] = make_uint2(lo, hi);
        }
    }
}

// ---------------- Kernel 2: LSTM, 2 blocks per image (round-10 protocol) ----------------
#define HPB 41
#define LROWS 42
__global__ __launch_bounds__(1024) void k_lstm(
    const uint2* __restrict__ xz, const float* __restrict__ wh,
    float* __restrict__ hout, int* __restrict__ gxi, int* __restrict__ flags)
{
    __shared__ float hb[2][LROWS * WW];
    __shared__ uint2 xt[2][2748];
    const int bid = blockIdx.x;
    const int b = bid >> 1, h = bid & 1;
    const int tid = threadIdx.x;

    float whr[9][4];
    #pragma unroll
    for (int k = 0; k < 9; ++k)
        #pragma unroll
        for (int g = 0; g < 4; ++g) whr[k][g] = wh[k * 4 + g];

    for (int i = tid; i < LROWS * WW; i += 1024) { hb[0][i] = 0.f; }

    const bool active = tid < 943;
    const int r  = active ? tid / 23 : 0;
    const int gr = h * HPB + r;
    const int lr = r + (h ? 1 : 0);
    const int x0 = (tid % 23) * 3;
    const int len = active ? ((x0 + 3 <= WW) ? 3 : (WW - x0)) : 0;
    const bool isb = active && ((h == 0 && r == 40) || (h == 1 && r == 0));
    float c[3];
    #pragma unroll
    for (int j = 0; j < 3; ++j) c[j] = 0.f;

    const int base_px = h ? 2746 : 0;
    const char* xzb = (const char*)xz + (((size_t)b * TT) * PIX + base_px) * 8;
    int* myflag = flags + bid;
    int* nbflag = flags + (bid ^ 1);
    const int gx_my = ((b * 2 + h) * 2) * 68;
    const int gx_nb = ((b * 2 + (h ^ 1)) * 2) * 68;

    #pragma unroll
    for (int k = 0; k < 2; ++k) {
        int idx = tid + k * 1024;
        if (idx < 1374)
            gload16(xzb + (size_t)idx * 16, (char*)xt[0] + (size_t)idx * 16);
    }
    __syncthreads();

    int cur = 0;
    #pragma unroll 1
    for (int t = 0; t < TT; ++t) {
        const int nxt = cur ^ 1;
        const int par = (t + 1) & 1;
        if (t < TT - 1) {
            const char* srcn = xzb + (size_t)(t + 1) * (PIX * 8);
            #pragma unroll
            for (int k = 0; k < 2; ++k) {
                int idx = tid + k * 1024;
                if (idx < 1374)
                    gload16(srcn + (size_t)idx * 16,
                            (char*)xt[nxt] + (size_t)idx * 16);
            }
        }
        if (active) {
            float z[3][4];
            #pragma unroll
            for (int j = 0; j < 3; ++j) {
                int xi = x0 + j; if (xi > WW - 1) xi = WW - 1;
                uint2 zp = xt[cur][gr * WW + xi - base_px];
                z[j][0] = bf16tof(zp.x); z[j][1] = bf16tof(zp.x >> 16);
                z[j][2] = bf16tof(zp.y); z[j][3] = bf16tof(zp.y >> 16);
            }
            #pragma unroll
            for (int ky = 0; ky < 3; ++ky) {
                int giy = gr + ky - 1;
                if (giy < 0 || giy >= HH) continue;
                const float* hr = &hb[cur][(giy - (h ? 40 : 0)) * WW];
                #pragma unroll
                for (int dx = -1; dx < 4; ++dx) {
                    int xi = x0 + dx;
                    if (xi < 0 || xi >= WW) continue;
                    float hv = hr[xi];
                    #pragma unroll
                    for (int kx = 0; kx < 3; ++kx) {
                        int xo = dx - kx + 1;
                        if (xo < 0 || xo > 2) continue;
                        #pragma unroll
                        for (int g = 0; g < 4; ++g)
                            z[xo][g] = fmaf(hv, whr[ky * 3 + kx][g], z[xo][g]);
                    }
                }
            }
            float* hw = &hb[nxt][lr * WW];
            #pragma unroll
            for (int j = 0; j < 3; ++j) {
                float fi = hsig(z[j][0]), ff = hsig(z[j][1]), fo = hsig(z[j][3]);
                float cn = ff * c[j] + fi * ftanh(z[j][2]);
                c[j] = cn;
                if (j < len) {
                    float hv = fo * ftanh(cn);
                    hw[x0 + j] = hv;
                    if (isb)
                        atomicExch(&gxi[gx_my + par * 68 + x0 + j],
                                   __float_as_int(hv));
                }
            }
        }
        __syncthreads();
        if (tid == 0) {
            atomicExch(myflag, t + 1);
            while (atomicAdd(nbflag, 0) < t + 1) { __builtin_amdgcn_s_sleep(8); }
        }
        __syncthreads();
        if (tid < WW) {
            int v = atomicAdd(&gxi[gx_nb + par * 68 + tid], 0);
            hb[nxt][(h ? 0 : 41) * WW + tid] = __int_as_float(v);
        }
        __syncthreads();
        cur = nxt;
    }
    float* ho = hout + (size_t)b * PIX + (size_t)h * 2747;
    const float* src = hb[cur] + (h ? WW : 0);
    for (int i = tid; i < 2747; i += 1024)
        ho[i] = src[i];
}

// ---------------- conv1 im2col: A1[m][192] bf16, m=(b,y,x) of [64][41][34] ----------------
__global__ __launch_bounds__(256) void k_im2col(
    const float* __restrict__ hin, const float* __restrict__ tar,
    uint* __restrict__ A1)
{
    const int id = blockIdx.x * 256 + threadIdx.x;
    const int p = id % 28;
    const int m = id / 28;
    if (m >= 89216) return;
    uint* dst = A1 + (size_t)m * 96;
    if (p >= 25) {
        uint* q = dst + 75 + (p - 25) * 7;
        #pragma unroll
        for (int i = 0; i < 7; ++i) q[i] = 0;
        return;
    }
    const int x = m % 34;
    const int y = (m / 34) % 41;
    const int b = m / 1394;
    const int ky = p / 5, kx = p % 5;
    const int iy = 2 * y + ky - 1;
    const int ix = 2 * x + kx - 2;
    float v[6] = {0.f, 0.f, 0.f, 0.f, 0.f, 0.f};
    if (iy >= 0 && iy < HH && ix >= 0 && ix < WW) {
        const int pi = b * PIX + iy * WW + ix;
        v[0] = hin[pi];
        const float* tp = tar + (size_t)pi * 5;
        #pragma unroll
        for (int c = 0; c < 5; ++c) v[c + 1] = tp[c];
    }
    uint* q = dst + p * 3;
    q[0] = bf16rne(v[0]) | (bf16rne(v[1]) << 16);
    q[1] = bf16rne(v[2]) | (bf16rne(v[3]) << 16);
    q[2] = bf16rne(v[4]) | (bf16rne(v[5]) << 16);
}

// ---------------- conv1 GEMM: 256M x 64N tile, K=192 (3 chunks), 4 waves on M ----------------
__global__ __launch_bounds__(256) void k_gemm1(
    const ushort* __restrict__ A1, const ushort* __restrict__ w1t,
    const float* __restrict__ b1, ushort* __restrict__ x1p)
{
    constexpr int M = 89216;
    __shared__ ushort At[256 * 64];
    __shared__ ushort Bl[64 * 64];

    const int tid = threadIdx.x;
    const int wid = tid >> 6, lane = tid & 63;
    const int m0 = blockIdx.x * 256;
    const int swz = (((lane & 7) ^ ((lane >> 3) & 7)) << 3);

    int arow[8], brow[2];
    #pragma unroll
    for (int i = 0; i < 8; ++i) {
        int row = wid * 64 + i * 8 + (lane >> 3);
        int m = m0 + row; if (m > M - 1) m = M - 1;
        arow[i] = m * 192;
    }
    #pragma unroll
    for (int i = 0; i < 2; ++i) {
        int row = wid * 16 + i * 8 + (lane >> 3);
        brow[i] = row * 192;
    }

    f32x4 acc[4][4];
    #pragma unroll
    for (int i = 0; i < 4; ++i)
        #pragma unroll
        for (int j = 0; j < 4; ++j) acc[i][j] = (f32x4){0.f, 0.f, 0.f, 0.f};

    #pragma unroll 1
    for (int kp = 0; kp < 3; ++kp) {
        const int koff = kp * 64;
        #pragma unroll
        for (int i = 0; i < 8; ++i)
            gload16(A1 + arow[i] + koff + swz,
                    (void*)(At + (wid * 64 + i * 8) * 64));
        #pragma unroll
        for (int i = 0; i < 2; ++i)
            gload16(w1t + brow[i] + koff + swz,
                    (void*)(Bl + (wid * 16 + i * 8) * 64));
        __syncthreads();
        #pragma unroll
        for (int ks = 0; ks < 2; ++ks) {
            short8 af[4], bf[4];
            const int lc = ks * 64 + ((lane >> 4) << 4);
            #pragma unroll
            for (int mf = 0; mf < 4; ++mf) {
                int row = wid * 64 + mf * 16 + (lane & 15);
                af[mf] = *(const short8*)((const char*)At + row * 128 + (lc ^ ((row & 7) << 4)));
            }
            #pragma unroll
            for (int nf = 0; nf < 4; ++nf) {
                int row = nf * 16 + (lane & 15);
                bf[nf] = *(const short8*)((const char*)Bl + row * 128 + (lc ^ ((row & 7) << 4)));
            }
            #pragma unroll
            for (int mf = 0; mf < 4; ++mf)
                #pragma unroll
                for (int nf = 0; nf < 4; ++nf)
                    acc[mf][nf] = __builtin_amdgcn_mfma_f32_16x16x32_bf16(
                        af[mf], bf[nf], acc[mf][nf], 0, 0, 0);
        }
        __syncthreads();
    }

    #pragma unroll
    for (int nf = 0; nf < 4; ++nf) {
        int n = nf * 16 + (lane & 15);
        float bias = b1[n];
        #pragma unroll
        for (int mf = 0; mf < 4; ++mf) {
            int mbase = m0 + wid * 64 + mf * 16 + ((lane >> 4) << 2);
            #pragma unroll
            for (int r = 0; r < 4; ++r) {
                int m = mbase + r;
                if (m < M) {
                    int x = m % 34, y = (m / 34) % 41, b = m / 1394;
                    float v = lrelu(acc[mf][nf][r] + bias);
                    x1p[((size_t)(b * 45 + y + 2) * 37 + (x + 1)) * 64 + n] =
                        (ushort)bf16rne(v);
                }
            }
        }
    }
}

// ---------------- MFMA implicit-GEMM conv (conv2 / conv3), 128M x 64N tile ----------------
template<bool IS3>
__global__ __launch_bounds__(256) void k_convm(
    const ushort* __restrict__ Ain, const ushort* __restrict__ Bt,
    const float* __restrict__ p0, const float* __restrict__ p1,
    const float* __restrict__ p2, const float* __restrict__ p3,
    ushort* __restrict__ outp)
{
    constexpr int OH = IS3 ? 20 : 21, OW = IS3 ? 16 : 17;
    constexpr int PH = IS3 ? 23 : 45, PW = IS3 ? 19 : 37;
    constexpr int CIN = IS3 ? 128 : 64;
    constexpr int KW_ = IS3 ? 4 : 5;
    constexpr int KK  = IS3 ? 16 : 25;
    constexpr int STR = IS3 ? 1 : 2;
    constexpr int HALVES = CIN / 64;
    constexpr int MPB = OH * OW;
    constexpr int M = 64 * MPB;
    constexpr int KTOT = KK * CIN;

    __shared__ ushort At[128 * 64];
    __shared__ ushort Bl[64 * 64];

    const int tid = threadIdx.x;
    const int wid = tid >> 6, lane = tid & 63;
    const int m0 = blockIdx.x * 128;
    const int n0 = blockIdx.y * 64;
    const int wr = wid >> 1, wc = wid & 1;

    const int swz = (((lane & 7) ^ ((lane >> 3) & 7)) << 3);

    int arow_base[4], brow_base[2];
    #pragma unroll
    for (int i = 0; i < 4; ++i) {
        int row = wid * 32 + i * 8 + (lane >> 3);
        int m = m0 + row; if (m > M - 1) m = M - 1;
        int b = m / MPB, r = m % MPB;
        int y = r / OW, x = r % OW;
        arow_base[i] = ((b * PH + y * STR) * PW + x * STR) * CIN;
    }
    #pragma unroll
    for (int i = 0; i < 2; ++i) {
        int row = wid * 16 + i * 8 + (lane >> 3);
        brow_base[i] = (n0 + row) * KTOT;
    }

    f32x4 acc[4][2];
    #pragma unroll
    for (int i = 0; i < 4; ++i)
        #pragma unroll
        for (int j = 0; j < 2; ++j) acc[i][j] = (f32x4){0.f, 0.f, 0.f, 0.f};

    #pragma unroll 1
    for (int kp = 0; kp < KK; ++kp) {
        const int ky = kp / KW_, kx = kp % KW_;
        const int aoff = (ky * PW + kx) * CIN;
        #pragma unroll
        for (int h = 0; h < HALVES; ++h) {
            const int koff = h * 64;
            #pragma unroll
            for (int i = 0; i < 4; ++i)
                gload16(Ain + arow_base[i] + aoff + koff + swz,
                        (void*)(At + (wid * 32 + i * 8) * 64));
            #pragma unroll
            for (int i = 0; i < 2; ++i)
                gload16(Bt + brow_base[i] + kp * CIN + koff + swz,
                        (void*)(Bl + (wid * 16 + i * 8) * 64));
            __syncthreads();
            #pragma unroll
            for (int ks = 0; ks < 2; ++ks) {
                short8 af[4], bf[2];
                const int lc = ks * 64 + ((lane >> 4) << 4);
                #pragma unroll
                for (int mf = 0; mf < 4; ++mf) {
                    int row = wr * 64 + mf * 16 + (lane & 15);
                    af[mf] = *(const short8*)((const char*)At + row * 128 + (lc ^ ((row & 7) << 4)));
                }
                #pragma unroll
                for (int nf = 0; nf < 2; ++nf) {
                    int row = wc * 32 + nf * 16 + (lane & 15);
                    bf[nf] = *(const short8*)((const char*)Bl + row * 128 + (lc ^ ((row & 7) << 4)));
                }
                #pragma unroll
                for (int mf = 0; mf < 4; ++mf)
                    #pragma unroll
                    for (int nf = 0; nf < 2; ++nf)
                        acc[mf][nf] = __builtin_amdgcn_mfma_f32_16x16x32_bf16(
                            af[mf], bf[nf], acc[mf][nf], 0, 0, 0);
            }
            __syncthreads();
        }
    }

    if (IS3) {
        #pragma unroll
        for (int nf = 0; nf < 2; ++nf) {
            int n = n0 + wc * 32 + nf * 16 + (lane & 15);
            float sc = p0[n] * rsqrtf(p3[n] + 1e-3f);
            float sh = p1[n] - p2[n] * sc;
            #pragma unroll
            for (int mf = 0; mf < 4; ++mf) {
                int mbase = m0 + wr * 64 + mf * 16 + ((lane >> 4) << 2);
                #pragma unroll
                for (int r = 0; r < 4; ++r) {
                    float v = lrelu(acc[mf][nf][r] * sc + sh);
                    outp[(size_t)(mbase + r) * 512 + n] = (ushort)bf16rne(v);
                }
            }
        }
    } else {
        #pragma unroll
        for (int nf = 0; nf < 2; ++nf) {
            int n = n0 + wc * 32 + nf * 16 + (lane & 15);
            float bias = p0[n];
            #pragma unroll
            for (int mf = 0; mf < 4; ++mf) {
                int mbase = m0 + wr * 64 + mf * 16 + ((lane >> 4) << 2);
                #pragma unroll
                for (int r = 0; r < 4; ++r) {
                    int m = mbase + r;
                    if (m < M) {
                        int b = m / MPB, rr = m % MPB;
                        int y = rr / OW, x = rr % OW;
                        float v = lrelu(acc[mf][nf][r] + bias);
                        outp[((size_t)((b * 23) + (y + 1)) * 19 + (x + 1)) * 128 + n] =
                            (ushort)bf16rne(v);
                    }
                }
            }
        }
    }
}

// ---------------- Kernel 6: conv4, 256-thread blocks, 4 waves split input-x ----------------
__global__ __launch_bounds__(256) void k_conv4(
    const ushort* __restrict__ x3, const float* __restrict__ w4,
    const float* __restrict__ b4, float* __restrict__ out)
{
    __shared__ float red[4][16];
    const int b = blockIdx.x / 19, y = blockIdx.x % 19;
    const int wid = threadIdx.x >> 6, lane = threadIdx.x & 63;
    const int c0 = lane * 8;
    float acc[15];
    #pragma unroll
    for (int x = 0; x < 15; ++x) acc[x] = 0.f;
    #pragma unroll 1
    for (int ky = 0; ky < 4; ++ky) {
        int iy = y + ky - 1;
        if (iy < 0 || iy >= 20) continue;
        float w[4][8];
        #pragma unroll
        for (int kx = 0; kx < 4; ++kx) {
            const float4 wa = *(const float4*)(w4 + (ky * 4 + kx) * 512 + c0);
            const float4 wb = *(const float4*)(w4 + (ky * 4 + kx) * 512 + c0 + 4);
            w[kx][0] = wa.x; w[kx][1] = wa.y; w[kx][2] = wa.z; w[kx][3] = wa.w;
            w[kx][4] = wb.x; w[kx][5] = wb.y; w[kx][6] = wb.z; w[kx][7] = wb.w;
        }
        #pragma unroll
        for (int ixl = 0; ixl < 4; ++ixl) {
            const int ix = wid * 4 + ixl;
            uint4 u = *(const uint4*)(x3 + ((size_t)(b * 20 + iy) * 16 + ix) * 512 + c0);
            float v[8];
            v[0] = bf16tof(u.x); v[1] = bf16tof(u.x >> 16);
            v[2] = bf16tof(u.y); v[3] = bf16tof(u.y >> 16);
            v[4] = bf16tof(u.z); v[5] = bf16tof(u.z >> 16);
            v[6] = bf16tof(u.w); v[7] = bf16tof(u.w >> 16);
            #pragma unroll
            for (int kx = 0; kx < 4; ++kx) {
                int x = ix - kx + 1;
                if (x < 0 || x > 14) continue;
                float s = 0.f;
                #pragma unroll
                for (int c = 0; c < 8; ++c) s = fmaf(v[c], w[kx][c], s);
                acc[x] += s;
            }
        }
    }
    #pragma unroll
    for (int x = 0; x < 15; ++x) {
        float s = acc[x];
        #pragma unroll
        for (int off = 32; off > 0; off >>= 1)
            s += __shfl_down(s, off);
        if (lane == 0) red[wid][x] = s;
    }
    __syncthreads();
    if (threadIdx.x < 15) {
        float s = red[0][threadIdx.x] + red[1][threadIdx.x] +
                  red[2][threadIdx.x] + red[3][threadIdx.x] + b4[0];
        out[(size_t)blockIdx.x * 15 + threadIdx.x] = s;
    }
}

extern "C" void kernel_launch(void* const* d_in, const int* in_sizes, int n_in,
                              void* d_out, int out_size, void* d_ws, size_t ws_size,
                              hipStream_t stream)
{
    const float* inp  = (const float*)d_in[0];
    const float* tar  = (const float*)d_in[1];
    const float* wx   = (const float*)d_in[2];
    const float* wh   = (const float*)d_in[3];
    const float* bl   = (const float*)d_in[4];
    const float* w1   = (const float*)d_in[5];
    const float* b1   = (const float*)d_in[6];
    const float* w2   = (const float*)d_in[7];
    const float* b2   = (const float*)d_in[8];
    const float* w3   = (const float*)d_in[9];
    const float* gam  = (const float*)d_in[10];
    const float* bet  = (const float*)d_in[11];
    const float* mean = (const float*)d_in[12];
    const float* var  = (const float*)d_in[13];
    const float* w4   = (const float*)d_in[14];
    const float* b4   = (const float*)d_in[15];
    float* out = (float*)d_out;

    char* ws = (char*)d_ws;
    uint2*  xz    = (uint2*)(ws);
    ushort* A1    = (ushort*)(ws);
    ushort* x3b   = (ushort*)(ws);
    float*  hfin  = (float*)(ws + 67510272);
    ushort* x1p   = (ushort*)(ws + 68916736);
    ushort* x2p   = (ushort*)(ws + 82556416);
    ushort* w2t   = (ushort*)(ws + 89716224);
    ushort* w3t   = (ushort*)(ws + 90125824);
    ushort* w1t   = (ushort*)(ws + 92222976);
    int*    gxi   = (int*)(ws + 92247552);
    int*    flags = (int*)(ws + 92386816);

    k_xz<<<NXZ + NPREP, 256, 0, stream>>>(inp, wx, bl, xz,
                                          w1, w2, w3, w1t, w2t, w3t,
                                          (uint4*)x1p, (uint4*)x2p, (uint4*)flags);
    k_lstm<<<BB * 2, 1024, 0, stream>>>(xz, wh, hfin, gxi, flags);

    k_im2col<<<(89216 * 28 + 255) / 256, 256, 0, stream>>>(hfin, tar, (uint*)A1);
    k_gemm1<<<349, 256, 0, stream>>>(A1, w1t, b1, x1p);

    dim3 g2(179, 2);
    k_convm<false><<<g2, 256, 0, stream>>>(x1p, w2t, b2, nullptr, nullptr, nullptr, x2p);
    dim3 g3(160, 8);
    k_convm<true><<<g3, 256, 0, stream>>>(x2p, w3t, gam, bet, mean, var, x3b);

    k_conv4<<<BB * 19, 256, 0, stream>>>(x3b, w4, b4, out);
}